// Round 3
// baseline (2286.466 us; speedup 1.0000x reference)
//
#include <hip/hip_runtime.h>

// ---------------------------------------------------------------------------
// MultiEdgeClassifier: 6-layer GCN + BN + weighted residual + edge-pair FC
// N=100k nodes, HID=128, E=1.6M edges (+N self loops), E_OUT=400k
// Round 2: src-tiled SpMM (L2-resident gathers) + register accumulators.
// ---------------------------------------------------------------------------

#define TS 12288           // src-tile size (3MB of bf16 h rows) -> 9 tiles for N=100k
#define RPW 13             // dst rows per wave (register accumulators)

typedef __attribute__((ext_vector_type(8))) short short8;
typedef __attribute__((ext_vector_type(4))) float f32x4;

static __device__ __forceinline__ unsigned short f2bf(float f) {
  unsigned u = __float_as_uint(f);
  u = u + 0x7fffu + ((u >> 16) & 1u);   // RNE
  return (unsigned short)(u >> 16);
}
static __device__ __forceinline__ float bf2f_lo(unsigned v) {
  return __uint_as_float(v << 16);
}
static __device__ __forceinline__ float bf2f_hi(unsigned v) {
  return __uint_as_float(v & 0xffff0000u);
}
static __device__ __forceinline__ unsigned pack_bf2(float a, float b) {
  return (unsigned)f2bf(a) | ((unsigned)f2bf(b) << 16);
}

// ---------------- preprocessing ----------------

__global__ void count_deg_kernel(const int* __restrict__ dst, int* __restrict__ cnt, int e) {
  int j = blockIdx.x * blockDim.x + threadIdx.x;
  if (j < e) atomicAdd(&cnt[dst[j]], 1);
}

__global__ void compute_dis_kernel(const int* __restrict__ cnt, float* __restrict__ dis, int n) {
  int i = blockIdx.x * blockDim.x + threadIdx.x;
  if (i < n) dis[i] = rsqrtf((float)(cnt[i] + 1));  // +1 self loop
}

// count edges (and self loops) per key = (src/TS)*n + dst
__global__ void count_key_kernel(const int* __restrict__ src, const int* __restrict__ dst,
                                 int* __restrict__ cnt2, int e, int n) {
  int j = blockIdx.x * blockDim.x + threadIdx.x;
  if (j >= e + n) return;
  int s, d;
  if (j < e) { s = src[j]; d = dst[j]; } else { s = j - e; d = j - e; }
  int key = (s / TS) * n + d;
  atomicAdd(&cnt2[key], 1);
}

// exclusive scan, 4096 elements per block (16 per thread)
__global__ void scan4k_block_kernel(const int* __restrict__ cnt, int* __restrict__ rs,
                                    int* __restrict__ partials, int n) {
  __shared__ int lds[256];
  int t = threadIdx.x;
  int base = blockIdx.x * 4096 + t * 16;
  int v[16]; int si = 0;
#pragma unroll
  for (int i = 0; i < 16; ++i) {
    int j = base + i;
    int x = (j < n) ? cnt[j] : 0;
    v[i] = x; si += x;
  }
  int val = si;
  lds[t] = val; __syncthreads();
  for (int off = 1; off < 256; off <<= 1) {
    int x = (t >= off) ? lds[t - off] : 0;
    __syncthreads();
    val += x;
    lds[t] = val;
    __syncthreads();
  }
  if (t == 255) partials[blockIdx.x] = val;
  int run = val - si;
#pragma unroll
  for (int i = 0; i < 16; ++i) {
    int j = base + i;
    if (j < n) rs[j] = run;
    run += v[i];
  }
}

__global__ void scan_partials_kernel(int* __restrict__ partials, int nb) {
  __shared__ int lds[256];
  int t = threadIdx.x;
  int v = (t < nb) ? partials[t] : 0;
  int val = v;
  lds[t] = val; __syncthreads();
  for (int off = 1; off < 256; off <<= 1) {
    int x = (t >= off) ? lds[t - off] : 0;
    __syncthreads();
    val += x;
    lds[t] = val;
    __syncthreads();
  }
  if (t < nb) partials[t] = val - v;
}

__global__ void scan_add_kernel(int* __restrict__ rs, const int* __restrict__ partials,
                                int n, int total) {
  int j = blockIdx.x * blockDim.x + threadIdx.x;
  if (j < n) rs[j] += partials[j >> 12];
  if (j == 0) rs[n] = total;
}

// counting-sort edges by key into packed (src, norm) records
__global__ void scatter_edges_kernel(const int* __restrict__ src, const int* __restrict__ dst,
                                     const float* __restrict__ dis, int* __restrict__ fill,
                                     int2* __restrict__ esn, int e, int n) {
  int j = blockIdx.x * blockDim.x + threadIdx.x;
  if (j >= e + n) return;
  int s, d;
  if (j < e) { s = src[j]; d = dst[j]; } else { s = j - e; d = j - e; }
  float nm = dis[s] * dis[d];
  int key = (s / TS) * n + d;
  int pos = atomicAdd(&fill[key], 1);
  esn[pos] = make_int2(s, __float_as_int(nm));
}

__global__ void softmax_w_kernel(const float* __restrict__ lw, float* __restrict__ w, int l) {
  if (threadIdx.x == 0 && blockIdx.x == 0) {
    float m = lw[0];
    for (int i = 1; i < l; ++i) m = fmaxf(m, lw[i]);
    float s = 0.f;
    for (int i = 0; i < l; ++i) s += expf(lw[i] - m);
    for (int i = 0; i < l; ++i) w[i] = expf(lw[i] - m) / s;
  }
}

// transpose conv_W to Wt[l][n][k] bf16
__global__ void transpose_w_kernel(const float* __restrict__ W, unsigned short* __restrict__ Wt,
                                   int total) {
  int t = blockIdx.x * blockDim.x + threadIdx.x;
  if (t >= total) return;
  int l = t >> 14;
  int nc = (t >> 7) & 127;
  int kk = t & 127;
  Wt[t] = f2bf(W[(size_t)l * 16384 + kk * 128 + nc]);
}

// ---------------- embed ----------------

__global__ void embed_kernel(const float* __restrict__ x, const float* __restrict__ W,
                             const float* __restrict__ b, float* __restrict__ xe,
                             unsigned short* __restrict__ xebf, int n) {
  int r = blockIdx.x * 2 + (threadIdx.x >> 7);
  int c = threadIdx.x & 127;
  if (r >= n) return;
  float acc = b[c];
#pragma unroll
  for (int k = 0; k < 16; ++k)
    acc = fmaf(x[(size_t)r * 16 + k], W[k * 128 + c], acc);
  xe[(size_t)r * 128 + c] = acc;
  xebf[(size_t)r * 128 + c] = f2bf(acc);
}

// ---------------- bf16 MFMA GEMM ----------------

__global__ __launch_bounds__(256) void gemm_mfma_kernel(const unsigned short* __restrict__ Abf,
                                                        const unsigned short* __restrict__ Wt,
                                                        unsigned short* __restrict__ Hbf,
                                                        int n) {
  int tid = threadIdx.x;
  int wid = tid >> 6, lane = tid & 63;
  int wr = wid >> 1, wc = wid & 1;
  int lrow = lane & 15, lk = lane >> 4;

  short8 wfrag[4][4];
  const short* WtS = (const short*)Wt;
#pragma unroll
  for (int n0 = 0; n0 < 4; ++n0) {
    int col = wc * 64 + n0 * 16 + lrow;
#pragma unroll
    for (int ks = 0; ks < 4; ++ks)
      wfrag[n0][ks] = *(const short8*)(WtS + (size_t)col * 128 + ks * 32 + lk * 8);
  }

  const short* AS = (const short*)Abf;
  int ntiles = (n + 31) >> 5;
  for (int tile = blockIdx.x; tile < ntiles; tile += gridDim.x) {
    int row = tile * 32 + wr * 16 + lrow;
    short8 afrag[4];
    if (row < n) {
#pragma unroll
      for (int ks = 0; ks < 4; ++ks)
        afrag[ks] = *(const short8*)(AS + (size_t)row * 128 + ks * 32 + lk * 8);
    } else {
#pragma unroll
      for (int ks = 0; ks < 4; ++ks) afrag[ks] = (short8)0;
    }
    f32x4 acc[4];
#pragma unroll
    for (int n0 = 0; n0 < 4; ++n0) acc[n0] = (f32x4)0.f;
#pragma unroll
    for (int ks = 0; ks < 4; ++ks)
#pragma unroll
      for (int n0 = 0; n0 < 4; ++n0)
        acc[n0] = __builtin_amdgcn_mfma_f32_16x16x32_bf16(afrag[ks], wfrag[n0][ks], acc[n0],
                                                          0, 0, 0);
    int orow0 = tile * 32 + wr * 16 + lk * 4;
#pragma unroll
    for (int n0 = 0; n0 < 4; ++n0) {
      int col = wc * 64 + n0 * 16 + lrow;
#pragma unroll
      for (int r = 0; r < 4; ++r) {
        int orow = orow0 + r;
        if (orow < n) Hbf[(size_t)orow * 128 + col] = f2bf(acc[n0][r]);
      }
    }
  }
}

// ---------------- src-tiled SpMM + fused BN stats ----------------
// 9 passes over src tiles; gathers stay in a 3MB L2-resident window.
// Each wave owns RPW contiguous dst rows; fp32 accumulators live in VGPRs
// across all passes; bf16 agg + BN stats written once at the end.

__global__ __launch_bounds__(256) void spmm_kernel(const int* __restrict__ rs2,
                                                   const int2* __restrict__ esn,
                                                   const unsigned* __restrict__ hb,
                                                   const float* __restrict__ bias,
                                                   unsigned* __restrict__ aggbf,
                                                   float* __restrict__ stats, int n, int nt) {
  int tid = threadIdx.x;
  int wid = tid >> 6, lane = tid & 63;
  int wave = blockIdx.x * 4 + wid;
  int r0 = wave * RPW;

  float aL[RPW], aH[RPW];
#pragma unroll
  for (int k = 0; k < RPW; ++k) { aL[k] = 0.f; aH[k] = 0.f; }

  for (int t = 0; t < nt; ++t) {
    const int* rsb = rs2 + (size_t)t * n;
#pragma unroll
    for (int k = 0; k < RPW; ++k) {
      int row = r0 + k;
      if (row >= n) continue;
      int e0 = rsb[row], e1 = rsb[row + 1];  // contiguous buckets: end = next start
      float s0 = 0.f, s1 = 0.f;
      int e = e0;
      for (; e + 2 <= e1; e += 2) {
        int2 pa = esn[e], pb = esn[e + 1];
        unsigned va = hb[(size_t)pa.x * 64 + lane];
        unsigned vb = hb[(size_t)pb.x * 64 + lane];
        float na = __int_as_float(pa.y), nb = __int_as_float(pb.y);
        s0 = fmaf(na, bf2f_lo(va), s0); s1 = fmaf(na, bf2f_hi(va), s1);
        s0 = fmaf(nb, bf2f_lo(vb), s0); s1 = fmaf(nb, bf2f_hi(vb), s1);
      }
      if (e < e1) {
        int2 p = esn[e];
        unsigned v = hb[(size_t)p.x * 64 + lane];
        float nm = __int_as_float(p.y);
        s0 = fmaf(nm, bf2f_lo(v), s0); s1 = fmaf(nm, bf2f_hi(v), s1);
      }
      aL[k] += s0; aH[k] += s1;
    }
  }

  // epilogue: bias, store bf16 agg, accumulate BN stats
  float b0 = bias[2 * lane], b1 = bias[2 * lane + 1];
  float s0 = 0.f, s1 = 0.f, q0 = 0.f, q1 = 0.f;
#pragma unroll
  for (int k = 0; k < RPW; ++k) {
    int row = r0 + k;
    if (row < n) {
      float x0 = aL[k] + b0, x1 = aH[k] + b1;
      aggbf[(size_t)row * 64 + lane] = pack_bf2(x0, x1);
      s0 += x0; s1 += x1;
      q0 = fmaf(x0, x0, q0); q1 = fmaf(x1, x1, q1);
    }
  }
  __shared__ float red[4][256];
  red[0][tid] = s0; red[1][tid] = s1; red[2][tid] = q0; red[3][tid] = q1;
  __syncthreads();
  float v = red[wid][lane] + red[wid][64 + lane] + red[wid][128 + lane] + red[wid][192 + lane];
  int c = (wid == 0) ? (2 * lane) : (wid == 1) ? (2 * lane + 1)
        : (wid == 2) ? (128 + 2 * lane) : (129 + 2 * lane);
  atomicAdd(&stats[c], v);
}

// ---------------- fused BN + ReLU + weighted residual ----------------

__global__ void bn_apply_kernel(const unsigned* __restrict__ aggbf,
                                const float* __restrict__ stats,
                                const float* __restrict__ gamma, const float* __restrict__ beta,
                                const float* __restrict__ wsm, int layer,
                                float* __restrict__ xe, unsigned* __restrict__ xebf2, int n) {
  int idx = blockIdx.x * blockDim.x + threadIdx.x;
  if (idx >= n * 64) return;
  int lpos = idx & 63;
  int c0 = 2 * lpos, c1 = c0 + 1;
  float w = wsm[layer];
  float invn = 1.f / (float)n;
  float m0 = stats[c0] * invn, m1 = stats[c1] * invn;
  float var0 = stats[128 + c0] * invn - m0 * m0;
  float var1 = stats[128 + c1] * invn - m1 * m1;
  float sc0 = gamma[c0] * rsqrtf(var0 + 1e-5f);
  float sc1 = gamma[c1] * rsqrtf(var1 + 1e-5f);
  float sh0 = beta[c0] - m0 * sc0;
  float sh1 = beta[c1] - m1 * sc1;
  unsigned av = aggbf[idx];
  float2 xv = *(const float2*)(xe + (size_t)idx * 2);
  float v0 = fmaxf(fmaf(bf2f_lo(av), sc0, sh0), 0.f);
  float v1 = fmaxf(fmaf(bf2f_hi(av), sc1, sh1), 0.f);
  float xn0 = fmaf(w, v0, xv.x);
  float xn1 = fmaf(w, v1, xv.y);
  *(float2*)(xe + (size_t)idx * 2) = make_float2(xn0, xn1);
  xebf2[idx] = pack_bf2(xn0, xn1);
}

// ---------------- final FC via linearity (reads bf16 x) ----------------

__global__ __launch_bounds__(256) void fc_node_kernel(const unsigned* __restrict__ xebf,
                                                      const float* __restrict__ fcW,
                                                      float* __restrict__ y, int n) {
  int wid = threadIdx.x >> 6;
  int lane = threadIdx.x & 63;
  int r = blockIdx.x * 4 + wid;
  if (r >= n) return;
  unsigned xv = xebf[(size_t)r * 64 + lane];
  float x0 = bf2f_lo(xv), x1 = bf2f_hi(xv);
  int k0 = lane * 2, k1 = lane * 2 + 1;
  float a00 = x0 * fcW[k0 * 2 + 0] + x1 * fcW[k1 * 2 + 0];
  float a01 = x0 * fcW[k0 * 2 + 1] + x1 * fcW[k1 * 2 + 1];
  float a10 = x0 * fcW[(128 + k0) * 2 + 0] + x1 * fcW[(128 + k1) * 2 + 0];
  float a11 = x0 * fcW[(128 + k0) * 2 + 1] + x1 * fcW[(128 + k1) * 2 + 1];
#pragma unroll
  for (int off = 32; off; off >>= 1) {
    a00 += __shfl_down(a00, off);
    a01 += __shfl_down(a01, off);
    a10 += __shfl_down(a10, off);
    a11 += __shfl_down(a11, off);
  }
  if (lane == 0) *(float4*)(y + (size_t)r * 4) = make_float4(a00, a01, a10, a11);
}

__global__ void edge_out_kernel(const float* __restrict__ y, const int* __restrict__ eo,
                                const float* __restrict__ fcb, float* __restrict__ out, int m) {
  int j = blockIdx.x * blockDim.x + threadIdx.x;
  if (j >= m) return;
  int a = eo[j], b = eo[m + j];
  float4 ya = *(const float4*)(y + (size_t)a * 4);
  float4 yb = *(const float4*)(y + (size_t)b * 4);
  out[(size_t)j * 2 + 0] = ya.x + yb.z + fcb[0];
  out[(size_t)j * 2 + 1] = ya.y + yb.w + fcb[1];
}

// ---------------------------------------------------------------------------

extern "C" void kernel_launch(void* const* d_in, const int* in_sizes, int n_in,
                              void* d_out, int out_size, void* d_ws, size_t ws_size,
                              hipStream_t stream) {
  const float* x     = (const float*)d_in[0];
  const int*   ei    = (const int*)d_in[1];
  const int*   eo    = (const int*)d_in[2];
  const float* embW  = (const float*)d_in[3];
  const float* embB  = (const float*)d_in[4];
  const float* convW = (const float*)d_in[5];
  const float* convB = (const float*)d_in[6];
  const float* gamma = (const float*)d_in[7];
  const float* beta  = (const float*)d_in[8];
  const float* lw    = (const float*)d_in[9];
  const float* fcW   = (const float*)d_in[10];
  const float* fcb   = (const float*)d_in[11];
  float* out = (float*)d_out;

  const int n = in_sizes[0] / 16;          // 100000
  const int e = in_sizes[1] / 2;           // 1600000
  const int m = in_sizes[2] / 2;           // 400000
  const int L = in_sizes[5] / (128 * 128); // 6

  const int nt = (n + TS - 1) / TS;        // 9 src tiles
  const int nk = nt * n;                   // 900000 keys

  const int* esrc = ei;
  const int* edst = ei + e;

  char* wsp = (char*)d_ws;
  size_t off = 0;
  auto take = [&](size_t bytes) -> void* {
    void* p = wsp + off;
    off = (off + bytes + 255) & ~(size_t)255;
    return p;
  };
  int*            cnt      = (int*)take((size_t)n * 4);
  int*            cnt2     = (int*)take((size_t)nk * 4);
  int*            rs2      = (int*)take((size_t)(nk + 1) * 4);
  int*            fill2    = (int*)take((size_t)nk * 4);
  float*          dis      = (float*)take((size_t)n * 4);
  int*            partials = (int*)take(256 * 4);
  float*          wsm      = (float*)take(64 * 4);
  float*          stats    = (float*)take((size_t)L * 256 * 4);
  int2*           esn      = (int2*)take((size_t)(e + n) * 8);
  float*          xe       = (float*)take((size_t)n * 128 * 4);
  unsigned short* xebf     = (unsigned short*)take((size_t)n * 128 * 2);
  unsigned short* hbf      = (unsigned short*)take((size_t)n * 128 * 2);
  unsigned*       aggbf    = (unsigned*)take((size_t)n * 64 * 4);
  unsigned short* Wt       = (unsigned short*)take((size_t)L * 128 * 128 * 2);
  float*          y        = (float*)take((size_t)n * 4 * 4);
  if (off > ws_size) return;

  const int nb_scan = (nk + 4095) / 4096;  // 220 <= 256

  // --- preprocessing ---
  hipMemsetAsync(cnt, 0, (size_t)n * 4, stream);
  hipMemsetAsync(cnt2, 0, (size_t)nk * 4, stream);
  hipMemsetAsync(stats, 0, (size_t)L * 256 * 4, stream);
  count_deg_kernel<<<(e + 255) / 256, 256, 0, stream>>>(edst, cnt, e);
  compute_dis_kernel<<<(n + 255) / 256, 256, 0, stream>>>(cnt, dis, n);
  count_key_kernel<<<(e + n + 255) / 256, 256, 0, stream>>>(esrc, edst, cnt2, e, n);
  scan4k_block_kernel<<<nb_scan, 256, 0, stream>>>(cnt2, rs2, partials, nk);
  scan_partials_kernel<<<1, 256, 0, stream>>>(partials, nb_scan);
  scan_add_kernel<<<(nk + 255) / 256, 256, 0, stream>>>(rs2, partials, nk, e + n);
  hipMemcpyAsync(fill2, rs2, (size_t)nk * 4, hipMemcpyDeviceToDevice, stream);
  scatter_edges_kernel<<<(e + n + 255) / 256, 256, 0, stream>>>(esrc, edst, dis, fill2,
                                                                esn, e, n);
  softmax_w_kernel<<<1, 64, 0, stream>>>(lw, wsm, L);
  transpose_w_kernel<<<(L * 16384 + 255) / 256, 256, 0, stream>>>(convW, Wt, L * 16384);

  // --- embed ---
  embed_kernel<<<(n + 1) / 2, 256, 0, stream>>>(x, embW, embB, xe, xebf, n);

  // --- 6 GCN layers ---
  const int spmm_blocks = ((n + RPW - 1) / RPW + 3) / 4;  // 1924
  for (int i = 0; i < L; ++i) {
    gemm_mfma_kernel<<<1024, 256, 0, stream>>>(xebf, Wt + (size_t)i * 16384, hbf, n);
    spmm_kernel<<<spmm_blocks, 256, 0, stream>>>(rs2, esn, (const unsigned*)hbf,
                                                 convB + (size_t)i * 128, aggbf,
                                                 stats + (size_t)i * 256, n, nt);
    bn_apply_kernel<<<(n * 64 + 255) / 256, 256, 0, stream>>>(
        aggbf, stats + (size_t)i * 256, gamma + (size_t)i * 128, beta + (size_t)i * 128,
        wsm, i, xe, (unsigned*)xebf, n);
  }

  // --- final FC via linearity ---
  fc_node_kernel<<<(n + 3) / 4, 256, 0, stream>>>((const unsigned*)xebf, fcW, y, n);
  edge_out_kernel<<<(m + 255) / 256, 256, 0, stream>>>(y, eo, fcb, out, m);
}

// Round 4
// 891.548 us; speedup vs baseline: 2.5646x; 2.5646x over previous
//
#include <hip/hip_runtime.h>

// ---------------------------------------------------------------------------
// MultiEdgeClassifier: 6-layer GCN + BN + weighted residual + edge-pair FC
// N=100k nodes, HID=128, E=1.6M edges (+N self loops), E_OUT=400k
// Round 3: flat segmented SpMM (edge-balanced waves, 8-deep gather pipeline),
//          conv_b dropped (cancels under BN), BN fused into next GEMM / FC.
// ---------------------------------------------------------------------------

#define NW 8192      // waves for spmm (2048 blocks x 4)

typedef __attribute__((ext_vector_type(8))) short short8;
typedef __attribute__((ext_vector_type(4))) float f32x4;

static __device__ __forceinline__ unsigned short f2bf(float f) {
  unsigned u = __float_as_uint(f);
  u = u + 0x7fffu + ((u >> 16) & 1u);   // RNE
  return (unsigned short)(u >> 16);
}
static __device__ __forceinline__ float bf2f_lo(unsigned v) {
  return __uint_as_float(v << 16);
}
static __device__ __forceinline__ float bf2f_hi(unsigned v) {
  return __uint_as_float(v & 0xffff0000u);
}
static __device__ __forceinline__ unsigned pack_bf2(float a, float b) {
  return (unsigned)f2bf(a) | ((unsigned)f2bf(b) << 16);
}

// ---------------- preprocessing ----------------

__global__ void count_deg_kernel(const int* __restrict__ dst, int* __restrict__ cnt, int e) {
  int j = blockIdx.x * blockDim.x + threadIdx.x;
  if (j < e) atomicAdd(&cnt[dst[j]], 1);
}

__global__ void compute_dis_kernel(const int* __restrict__ cnt, float* __restrict__ dis, int n) {
  int i = blockIdx.x * blockDim.x + threadIdx.x;
  if (i < n) dis[i] = rsqrtf((float)(cnt[i] + 1));  // +1 self loop
}

// exclusive scan of (cnt[i]+1), 1024 elems per block
__global__ void scan_block_kernel(const int* __restrict__ cnt, int* __restrict__ rs,
                                  int* __restrict__ partials, int n) {
  __shared__ int lds[256];
  int t = threadIdx.x;
  int base = blockIdx.x * 1024 + t * 4;
  int v[4]; int si = 0;
#pragma unroll
  for (int i = 0; i < 4; ++i) {
    int j = base + i;
    int x = (j < n) ? (cnt[j] + 1) : 0;
    v[i] = x; si += x;
  }
  int val = si;
  lds[t] = val; __syncthreads();
  for (int off = 1; off < 256; off <<= 1) {
    int x = (t >= off) ? lds[t - off] : 0;
    __syncthreads();
    val += x;
    lds[t] = val;
    __syncthreads();
  }
  if (t == 255) partials[blockIdx.x] = val;
  int run = val - si;
#pragma unroll
  for (int i = 0; i < 4; ++i) {
    int j = base + i;
    if (j < n) rs[j] = run;
    run += v[i];
  }
}

__global__ void scan_partials_kernel(int* __restrict__ partials, int nb) {
  __shared__ int lds[256];
  int t = threadIdx.x;
  int v = (t < nb) ? partials[t] : 0;
  int val = v;
  lds[t] = val; __syncthreads();
  for (int off = 1; off < 256; off <<= 1) {
    int x = (t >= off) ? lds[t - off] : 0;
    __syncthreads();
    val += x;
    lds[t] = val;
    __syncthreads();
  }
  if (t < nb) partials[t] = val - v;
}

__global__ void scan_add_kernel(int* __restrict__ rs, const int* __restrict__ partials,
                                int n, int total) {
  int j = blockIdx.x * blockDim.x + threadIdx.x;
  if (j < n) rs[j] += partials[j >> 10];
  if (j == 0) rs[n] = total;
}

// counting-sort edges by dst into packed (src, norm) records
__global__ void scatter_edges_kernel(const int* __restrict__ src, const int* __restrict__ dst,
                                     const float* __restrict__ dis, int* __restrict__ fill,
                                     int2* __restrict__ esn, int e, int n) {
  int j = blockIdx.x * blockDim.x + threadIdx.x;
  if (j >= e + n) return;
  int s, d;
  if (j < e) { s = src[j]; d = dst[j]; } else { s = j - e; d = j - e; }
  float nm = dis[s] * dis[d];
  int pos = atomicAdd(&fill[d], 1);
  esn[pos] = make_int2(s, __float_as_int(nm));
}

// per-wave row bounds: A[w] = first row r with rs[r] >= w*EB
__global__ void wave_bounds_kernel(const int* __restrict__ rs, int* __restrict__ A,
                                   int n, int nw, int eb) {
  int w = blockIdx.x * blockDim.x + threadIdx.x;
  if (w > nw) return;
  int target = w * eb;
  int lo = 0, hi = n;
  while (lo < hi) {
    int mid = (lo + hi) >> 1;
    if (rs[mid] < target) lo = mid + 1; else hi = mid;
  }
  A[w] = lo;
}

__global__ void softmax_w_kernel(const float* __restrict__ lw, float* __restrict__ w, int l) {
  if (threadIdx.x == 0 && blockIdx.x == 0) {
    float m = lw[0];
    for (int i = 1; i < l; ++i) m = fmaxf(m, lw[i]);
    float s = 0.f;
    for (int i = 0; i < l; ++i) s += expf(lw[i] - m);
    for (int i = 0; i < l; ++i) w[i] = expf(lw[i] - m) / s;
  }
}

// transpose conv_W to Wt[l][n][k] bf16
__global__ void transpose_w_kernel(const float* __restrict__ W, unsigned short* __restrict__ Wt,
                                   int total) {
  int t = blockIdx.x * blockDim.x + threadIdx.x;
  if (t >= total) return;
  int l = t >> 14;
  int nc = (t >> 7) & 127;
  int kk = t & 127;
  Wt[t] = f2bf(W[(size_t)l * 16384 + kk * 128 + nc]);
}

// ---------------- embed ----------------

__global__ void embed_kernel(const float* __restrict__ x, const float* __restrict__ W,
                             const float* __restrict__ b, float* __restrict__ xe,
                             unsigned short* __restrict__ xebf, int n) {
  int r = blockIdx.x * 2 + (threadIdx.x >> 7);
  int c = threadIdx.x & 127;
  if (r >= n) return;
  float acc = b[c];
#pragma unroll
  for (int k = 0; k < 16; ++k)
    acc = fmaf(x[(size_t)r * 16 + k], W[k * 128 + c], acc);
  xe[(size_t)r * 128 + c] = acc;
  xebf[(size_t)r * 128 + c] = f2bf(acc);
}

// ---------------- fused (BN+ReLU+residual of prev layer) + MFMA GEMM ----------------
// 64-row tiles, 4 waves x 16 rows; W staged in LDS keyed (n0,ks,lane) -> conflict-free.
// HASBN: read agg(prev) + stats(prev), update xe in place, A-frag = bf16(xe_new).

template<bool HASBN>
__global__ __launch_bounds__(256) void gemm_fused_kernel(
    const unsigned short* __restrict__ Abf,   // !HASBN: bf16 input
    const unsigned* __restrict__ aggbf,       // HASBN: packed bf16x2 agg (prev layer)
    const float* __restrict__ stats8,         // HASBN: 8 slices x 256 (prev layer)
    const float* __restrict__ gamma, const float* __restrict__ beta,
    const float* __restrict__ wsm, int layer, // prev layer idx
    float* __restrict__ xe,
    const unsigned short* __restrict__ Wt,
    unsigned short* __restrict__ Hbf, int n) {
  __shared__ short8 wlds[2048];               // 32 KB
  __shared__ float sc_s[128], sh_s[128];
  int tid = threadIdx.x;
  const short* WtS = (const short*)Wt;
#pragma unroll
  for (int it = 0; it < 8; ++it) {
    int s = it * 256 + tid;
    int ln = s & 63, g = s >> 6;              // g = n0*4+ks
    int col = ((g >> 2) << 4) + (ln & 15);
    wlds[s] = *(const short8*)(WtS + (size_t)col * 128 + (g & 3) * 32 + (ln >> 4) * 8);
  }
  if (HASBN && tid < 128) {
    float s = 0.f, q = 0.f;
#pragma unroll
    for (int k = 0; k < 8; ++k) {
      s += stats8[k * 256 + tid];
      q += stats8[k * 256 + 128 + tid];
    }
    float invn = 1.f / (float)n;
    float mean = s * invn;
    float var = q * invn - mean * mean;
    float sc = gamma[tid] * rsqrtf(var + 1e-5f);
    sc_s[tid] = sc;
    sh_s[tid] = beta[tid] - mean * sc;
  }
  __syncthreads();

  int wid = tid >> 6, lane = tid & 63;
  int lrow = lane & 15, lk = lane >> 4;
  float wres = HASBN ? wsm[layer] : 0.f;

  int ntiles = (n + 63) >> 6;
  for (int tile = blockIdx.x; tile < ntiles; tile += gridDim.x) {
    int row = tile * 64 + wid * 16 + lrow;
    short8 afrag[4];
    if (row < n) {
      if (HASBN) {
        const unsigned* arow = aggbf + (size_t)row * 64;
        float* xrow = xe + (size_t)row * 128;
#pragma unroll
        for (int ks = 0; ks < 4; ++ks) {
          int c0 = ks * 32 + lk * 8;
          uint4 av = *(const uint4*)(arow + (c0 >> 1));
          float4 xa = *(const float4*)(xrow + c0);
          float4 xb = *(const float4*)(xrow + c0 + 4);
          unsigned aw[4] = {av.x, av.y, av.z, av.w};
          float xv[8] = {xa.x, xa.y, xa.z, xa.w, xb.x, xb.y, xb.z, xb.w};
          float xn[8];
          short8 af;
#pragma unroll
          for (int d = 0; d < 4; ++d) {
            int c = c0 + 2 * d;
            float v0 = fmaxf(fmaf(bf2f_lo(aw[d]), sc_s[c], sh_s[c]), 0.f);
            float v1 = fmaxf(fmaf(bf2f_hi(aw[d]), sc_s[c + 1], sh_s[c + 1]), 0.f);
            xn[2 * d]     = fmaf(wres, v0, xv[2 * d]);
            xn[2 * d + 1] = fmaf(wres, v1, xv[2 * d + 1]);
          }
          *(float4*)(xrow + c0)     = make_float4(xn[0], xn[1], xn[2], xn[3]);
          *(float4*)(xrow + c0 + 4) = make_float4(xn[4], xn[5], xn[6], xn[7]);
#pragma unroll
          for (int d2 = 0; d2 < 8; ++d2) af[d2] = (short)f2bf(xn[d2]);
          afrag[ks] = af;
        }
      } else {
        const short* AS = (const short*)Abf;
#pragma unroll
        for (int ks = 0; ks < 4; ++ks)
          afrag[ks] = *(const short8*)(AS + (size_t)row * 128 + ks * 32 + lk * 8);
      }
    } else {
#pragma unroll
      for (int ks = 0; ks < 4; ++ks) afrag[ks] = (short8)0;
    }
    f32x4 acc[8];
#pragma unroll
    for (int n0 = 0; n0 < 8; ++n0) acc[n0] = (f32x4)0.f;
#pragma unroll
    for (int ks = 0; ks < 4; ++ks)
#pragma unroll
      for (int n0 = 0; n0 < 8; ++n0)
        acc[n0] = __builtin_amdgcn_mfma_f32_16x16x32_bf16(
            afrag[ks], wlds[(n0 * 4 + ks) * 64 + lane], acc[n0], 0, 0, 0);
    int orow0 = tile * 64 + wid * 16 + lk * 4;
#pragma unroll
    for (int n0 = 0; n0 < 8; ++n0) {
      int col = n0 * 16 + lrow;
#pragma unroll
      for (int r = 0; r < 4; ++r) {
        int orow = orow0 + r;
        if (orow < n) Hbf[(size_t)orow * 128 + col] = f2bf(acc[n0][r]);
      }
    }
  }
}

// ---------------- flat segmented SpMM + fused BN stats ----------------
// Wave w owns rows [A[w], A[w+1]); streams its edges 8-deep; flushes at row ends.

#define SPMM_STEP(PI, VI, EOFF)                                            \
  {                                                                        \
    float nm = __int_as_float(PI.y);                                       \
    a0 = fmaf(nm, bf2f_lo(VI), a0);                                        \
    a1 = fmaf(nm, bf2f_hi(VI), a1);                                        \
    if (e + (EOFF) + 1 == next) {                                          \
      aggbf[(size_t)row * 64 + lane] = pack_bf2(a0, a1);                   \
      s0 += a0; s1 += a1;                                                  \
      q0 = fmaf(a0, a0, q0); q1 = fmaf(a1, a1, q1);                        \
      a0 = 0.f; a1 = 0.f;                                                  \
      ++row;                                                               \
      next = (row < row_end) ? rs[row + 1] : 0x7fffffff;                   \
    }                                                                      \
  }

__global__ __launch_bounds__(256) void spmm_kernel(
    const int* __restrict__ rs, const int* __restrict__ A,
    const int2* __restrict__ esn, const unsigned* __restrict__ hb,
    unsigned* __restrict__ aggbf, float* __restrict__ stats8, int n) {
  int tid = threadIdx.x;
  int wid = tid >> 6, lane = tid & 63;
  int w = blockIdx.x * 4 + wid;
  int row = A[w], row_end = A[w + 1];
  float s0 = 0.f, s1 = 0.f, q0 = 0.f, q1 = 0.f;
  if (row < row_end) {
    int e = rs[row];
    int eend = rs[row_end];
    int next = rs[row + 1];
    float a0 = 0.f, a1 = 0.f;
    while (e + 8 <= eend) {
      int2 p0 = esn[e],     p1 = esn[e + 1], p2 = esn[e + 2], p3 = esn[e + 3];
      int2 p4 = esn[e + 4], p5 = esn[e + 5], p6 = esn[e + 6], p7 = esn[e + 7];
      unsigned v0 = hb[(size_t)p0.x * 64 + lane];
      unsigned v1 = hb[(size_t)p1.x * 64 + lane];
      unsigned v2 = hb[(size_t)p2.x * 64 + lane];
      unsigned v3 = hb[(size_t)p3.x * 64 + lane];
      unsigned v4 = hb[(size_t)p4.x * 64 + lane];
      unsigned v5 = hb[(size_t)p5.x * 64 + lane];
      unsigned v6 = hb[(size_t)p6.x * 64 + lane];
      unsigned v7 = hb[(size_t)p7.x * 64 + lane];
      SPMM_STEP(p0, v0, 0) SPMM_STEP(p1, v1, 1) SPMM_STEP(p2, v2, 2) SPMM_STEP(p3, v3, 3)
      SPMM_STEP(p4, v4, 4) SPMM_STEP(p5, v5, 5) SPMM_STEP(p6, v6, 6) SPMM_STEP(p7, v7, 7)
      e += 8;
    }
    while (e < eend) {
      int2 p = esn[e];
      unsigned v = hb[(size_t)p.x * 64 + lane];
      SPMM_STEP(p, v, 0)
      ++e;
    }
  }
  __shared__ float red[4][256];
  red[0][tid] = s0; red[1][tid] = s1; red[2][tid] = q0; red[3][tid] = q1;
  __syncthreads();
  float v = red[wid][lane] + red[wid][64 + lane] + red[wid][128 + lane] + red[wid][192 + lane];
  int c = (wid == 0) ? (2 * lane) : (wid == 1) ? (2 * lane + 1)
        : (wid == 2) ? (128 + 2 * lane) : (129 + 2 * lane);
  atomicAdd(&stats8[(blockIdx.x & 7) * 256 + c], v);
}

// ---------------- final FC (fused BN of last layer) ----------------

__global__ __launch_bounds__(256) void fc_node_kernel(
    const unsigned* __restrict__ aggbf, const float* __restrict__ stats8,
    const float* __restrict__ gamma, const float* __restrict__ beta,
    const float* __restrict__ wsm, int layer,
    const float* __restrict__ xe, const float* __restrict__ fcW,
    float* __restrict__ y, int n) {
  __shared__ float sc_s[128], sh_s[128];
  int tid = threadIdx.x;
  if (tid < 128) {
    float s = 0.f, q = 0.f;
#pragma unroll
    for (int k = 0; k < 8; ++k) {
      s += stats8[k * 256 + tid];
      q += stats8[k * 256 + 128 + tid];
    }
    float invn = 1.f / (float)n;
    float mean = s * invn;
    float var = q * invn - mean * mean;
    float sc = gamma[tid] * rsqrtf(var + 1e-5f);
    sc_s[tid] = sc;
    sh_s[tid] = beta[tid] - mean * sc;
  }
  __syncthreads();
  int wid = tid >> 6, lane = tid & 63;
  int r = blockIdx.x * 4 + wid;
  if (r >= n) return;
  float w = wsm[layer];
  unsigned av = aggbf[(size_t)r * 64 + lane];
  float2 xv = *(const float2*)(xe + (size_t)r * 128 + lane * 2);
  int c0 = lane * 2, c1 = c0 + 1;
  float x0 = fmaf(w, fmaxf(fmaf(bf2f_lo(av), sc_s[c0], sh_s[c0]), 0.f), xv.x);
  float x1 = fmaf(w, fmaxf(fmaf(bf2f_hi(av), sc_s[c1], sh_s[c1]), 0.f), xv.y);
  float a00 = x0 * fcW[c0 * 2 + 0] + x1 * fcW[c1 * 2 + 0];
  float a01 = x0 * fcW[c0 * 2 + 1] + x1 * fcW[c1 * 2 + 1];
  float a10 = x0 * fcW[(128 + c0) * 2 + 0] + x1 * fcW[(128 + c1) * 2 + 0];
  float a11 = x0 * fcW[(128 + c0) * 2 + 1] + x1 * fcW[(128 + c1) * 2 + 1];
#pragma unroll
  for (int off = 32; off; off >>= 1) {
    a00 += __shfl_down(a00, off);
    a01 += __shfl_down(a01, off);
    a10 += __shfl_down(a10, off);
    a11 += __shfl_down(a11, off);
  }
  if (lane == 0) *(float4*)(y + (size_t)r * 4) = make_float4(a00, a01, a10, a11);
}

__global__ void edge_out_kernel(const float* __restrict__ y, const int* __restrict__ eo,
                                const float* __restrict__ fcb, float* __restrict__ out, int m) {
  int j = blockIdx.x * blockDim.x + threadIdx.x;
  if (j >= m) return;
  int a = eo[j], b = eo[m + j];
  float4 ya = *(const float4*)(y + (size_t)a * 4);
  float4 yb = *(const float4*)(y + (size_t)b * 4);
  out[(size_t)j * 2 + 0] = ya.x + yb.z + fcb[0];
  out[(size_t)j * 2 + 1] = ya.y + yb.w + fcb[1];
}

// ---------------------------------------------------------------------------

extern "C" void kernel_launch(void* const* d_in, const int* in_sizes, int n_in,
                              void* d_out, int out_size, void* d_ws, size_t ws_size,
                              hipStream_t stream) {
  const float* x     = (const float*)d_in[0];
  const int*   ei    = (const int*)d_in[1];
  const int*   eo    = (const int*)d_in[2];
  const float* embW  = (const float*)d_in[3];
  const float* embB  = (const float*)d_in[4];
  const float* convW = (const float*)d_in[5];
  const float* gamma = (const float*)d_in[7];
  const float* beta  = (const float*)d_in[8];
  const float* lw    = (const float*)d_in[9];
  const float* fcW   = (const float*)d_in[10];
  const float* fcb   = (const float*)d_in[11];
  float* out = (float*)d_out;

  const int n = in_sizes[0] / 16;          // 100000
  const int e = in_sizes[1] / 2;           // 1600000
  const int m = in_sizes[2] / 2;           // 400000
  const int L = in_sizes[5] / (128 * 128); // 6

  const int T  = e + n;                    // total edges incl self loops
  const int EB = (T + NW - 1) / NW;        // edges per wave target

  const int* esrc = ei;
  const int* edst = ei + e;

  char* wsp = (char*)d_ws;
  size_t off = 0;
  auto take = [&](size_t bytes) -> void* {
    void* p = wsp + off;
    off = (off + bytes + 255) & ~(size_t)255;
    return p;
  };
  int*            cnt      = (int*)take((size_t)n * 4);
  int*            rowstart = (int*)take((size_t)(n + 1) * 4);
  int*            fill     = (int*)take((size_t)n * 4);
  float*          dis      = (float*)take((size_t)n * 4);
  int*            partials = (int*)take(256 * 4);
  float*          wsm      = (float*)take(64 * 4);
  float*          stats    = (float*)take((size_t)L * 8 * 256 * 4);
  int*            A        = (int*)take((size_t)(NW + 1) * 4);
  int2*           esn      = (int2*)take((size_t)T * 8);
  float*          xe       = (float*)take((size_t)n * 128 * 4);
  unsigned short* xebf     = (unsigned short*)take((size_t)n * 128 * 2);
  unsigned short* hbf      = (unsigned short*)take((size_t)n * 128 * 2);
  unsigned*       aggbf    = (unsigned*)take((size_t)n * 64 * 4);
  unsigned short* Wt       = (unsigned short*)take((size_t)L * 128 * 128 * 2);
  float*          y        = (float*)take((size_t)n * 4 * 4);
  if (off > ws_size) return;

  const int nb_scan = (n + 1023) / 1024;   // 98

  // --- preprocessing ---
  hipMemsetAsync(cnt, 0, (size_t)n * 4, stream);
  hipMemsetAsync(stats, 0, (size_t)L * 8 * 256 * 4, stream);
  count_deg_kernel<<<(e + 255) / 256, 256, 0, stream>>>(edst, cnt, e);
  compute_dis_kernel<<<(n + 255) / 256, 256, 0, stream>>>(cnt, dis, n);
  scan_block_kernel<<<nb_scan, 256, 0, stream>>>(cnt, rowstart, partials, n);
  scan_partials_kernel<<<1, 256, 0, stream>>>(partials, nb_scan);
  scan_add_kernel<<<(n + 255) / 256, 256, 0, stream>>>(rowstart, partials, n, T);
  hipMemcpyAsync(fill, rowstart, (size_t)n * 4, hipMemcpyDeviceToDevice, stream);
  scatter_edges_kernel<<<(T + 255) / 256, 256, 0, stream>>>(esrc, edst, dis, fill, esn, e, n);
  wave_bounds_kernel<<<(NW + 256) / 256, 256, 0, stream>>>(rowstart, A, n, NW, EB);
  softmax_w_kernel<<<1, 64, 0, stream>>>(lw, wsm, L);
  transpose_w_kernel<<<(L * 16384 + 255) / 256, 256, 0, stream>>>(convW, Wt, L * 16384);

  // --- embed ---
  embed_kernel<<<(n + 1) / 2, 256, 0, stream>>>(x, embW, embB, xe, xebf, n);

  // --- 6 GCN layers (conv_b dropped: cancels under BN) ---
  for (int i = 0; i < L; ++i) {
    if (i == 0) {
      gemm_fused_kernel<false><<<1024, 256, 0, stream>>>(
          xebf, nullptr, nullptr, nullptr, nullptr, wsm, 0, xe,
          Wt, hbf, n);
    } else {
      gemm_fused_kernel<true><<<1024, 256, 0, stream>>>(
          nullptr, aggbf, stats + (size_t)(i - 1) * 2048,
          gamma + (size_t)(i - 1) * 128, beta + (size_t)(i - 1) * 128, wsm, i - 1, xe,
          Wt + (size_t)i * 16384, hbf, n);
    }
    spmm_kernel<<<NW / 4, 256, 0, stream>>>(rowstart, A, esn, (const unsigned*)hbf,
                                            aggbf, stats + (size_t)i * 2048, n);
  }

  // --- final FC (fused BN of layer L-1) ---
  fc_node_kernel<<<(n + 3) / 4, 256, 0, stream>>>(
      aggbf, stats + (size_t)(L - 1) * 2048,
      gamma + (size_t)(L - 1) * 128, beta + (size_t)(L - 1) * 128, wsm, L - 1,
      xe, fcW, y, n);
  edge_out_kernel<<<(m + 255) / 256, 256, 0, stream>>>(y, eo, fcb, out, m);
}

// Round 5
// 819.742 us; speedup vs baseline: 2.7893x; 1.0876x over previous
//
#include <hip/hip_runtime.h>

// ---------------------------------------------------------------------------
// MultiEdgeClassifier: 6-layer GCN + BN + weighted residual + edge-pair FC
// N=100k nodes, HID=128, E=1.6M edges (+N self loops), E_OUT=400k
// Round 4: two-level radix sort by dst (streaming writes) replaces the
//          random-scatter counting sort + count_deg + scans.
// ---------------------------------------------------------------------------

#define NW 8192      // waves for spmm (2048 blocks x 4)
#define BKT 128      // dsts per bucket
#define CAP 6144     // max edges per bucket staged in LDS (mean ~2175)

typedef __attribute__((ext_vector_type(8))) short short8;
typedef __attribute__((ext_vector_type(4))) float f32x4;

static __device__ __forceinline__ unsigned short f2bf(float f) {
  unsigned u = __float_as_uint(f);
  u = u + 0x7fffu + ((u >> 16) & 1u);   // RNE
  return (unsigned short)(u >> 16);
}
static __device__ __forceinline__ float bf2f_lo(unsigned v) {
  return __uint_as_float(v << 16);
}
static __device__ __forceinline__ float bf2f_hi(unsigned v) {
  return __uint_as_float(v & 0xffff0000u);
}
static __device__ __forceinline__ unsigned pack_bf2(float a, float b) {
  return (unsigned)f2bf(a) | ((unsigned)f2bf(b) << 16);
}

// ---------------- preprocessing: two-level radix sort by dst ----------------

// pass A: per-bucket histogram (bucket = dst >> 7)
__global__ __launch_bounds__(256) void hist_bucket_kernel(const int* __restrict__ dst,
                                                          int* __restrict__ bcnt,
                                                          int e, int n, int nbk) {
  __shared__ int h[1024];
  int T = e + n;
  int chunk = (T + gridDim.x - 1) / gridDim.x;
  int j0 = blockIdx.x * chunk;
  int j1 = min(j0 + chunk, T);
  for (int i = threadIdx.x; i < nbk; i += 256) h[i] = 0;
  __syncthreads();
  for (int j = j0 + threadIdx.x; j < j1; j += 256) {
    int d = (j < e) ? dst[j] : (j - e);
    atomicAdd(&h[d >> 7], 1);
  }
  __syncthreads();
  for (int i = threadIdx.x; i < nbk; i += 256)
    if (h[i]) atomicAdd(&bcnt[i], h[i]);
}

// pass B prep: exclusive scan of bucket counts (single block)
__global__ __launch_bounds__(1024) void scan_buckets_kernel(const int* __restrict__ bcnt,
                                                            int* __restrict__ bbase,
                                                            int nbk, int total) {
  __shared__ int lds[1024];
  int t = threadIdx.x;
  int v = (t < nbk) ? bcnt[t] : 0;
  int val = v;
  lds[t] = val; __syncthreads();
  for (int off = 1; off < 1024; off <<= 1) {
    int x = (t >= off) ? lds[t - off] : 0;
    __syncthreads();
    val += x;
    lds[t] = val;
    __syncthreads();
  }
  if (t < nbk) bbase[t] = val - v;
  if (t == 0) bbase[nbk] = total;
}

// pass B: scatter edges into bucket regions (contiguous per (block,bucket))
__global__ __launch_bounds__(256) void scatter_bucket_kernel(const int* __restrict__ src,
                                                             const int* __restrict__ dst,
                                                             int* __restrict__ bfill,
                                                             int2* __restrict__ ebuf,
                                                             int e, int n, int nbk) {
  __shared__ int cntL[1024], baseL[1024];
  int T = e + n;
  int chunk = (T + gridDim.x - 1) / gridDim.x;
  int j0 = blockIdx.x * chunk;
  int j1 = min(j0 + chunk, T);
  for (int i = threadIdx.x; i < nbk; i += 256) cntL[i] = 0;
  __syncthreads();
  for (int j = j0 + threadIdx.x; j < j1; j += 256) {
    int d = (j < e) ? dst[j] : (j - e);
    atomicAdd(&cntL[d >> 7], 1);
  }
  __syncthreads();
  for (int i = threadIdx.x; i < nbk; i += 256) {
    int c = cntL[i];
    baseL[i] = c ? atomicAdd(&bfill[i], c) : 0;
    cntL[i] = 0;
  }
  __syncthreads();
  for (int j = j0 + threadIdx.x; j < j1; j += 256) {
    int s, d;
    if (j < e) { s = src[j]; d = dst[j]; } else { s = j - e; d = s; }
    int b = d >> 7;
    int r = atomicAdd(&cntL[b], 1);
    ebuf[baseL[b] + r] = make_int2(s, d);
  }
}

// pass C: in-LDS sort of each bucket by dst; emits rs, dis, sorted (src,dst)
__global__ __launch_bounds__(256) void sort_bucket_kernel(const int* __restrict__ bbase,
                                                          const int2* __restrict__ ebuf,
                                                          int2* __restrict__ ebuf2,
                                                          int* __restrict__ rs,
                                                          float* __restrict__ dis,
                                                          int n, int total) {
  __shared__ int2 el[CAP];
  __shared__ int hist[BKT], excl[BKT], cur[BKT], scn[BKT];
  int b = blockIdx.x, t = threadIdx.x;
  int e0 = bbase[b], e1 = bbase[b + 1];
  int sz = e1 - e0;
  bool inl = (sz <= CAP);
  if (inl)
    for (int i = t; i < sz; i += 256) el[i] = ebuf[e0 + i];
  if (t < BKT) hist[t] = 0;
  __syncthreads();
  for (int i = t; i < sz; i += 256) {
    int d = inl ? el[i].y : ebuf[e0 + i].y;
    atomicAdd(&hist[d & (BKT - 1)], 1);
  }
  __syncthreads();
  int val = (t < BKT) ? hist[t] : 0;
  if (t < BKT) scn[t] = val;
  __syncthreads();
  for (int off = 1; off < BKT; off <<= 1) {
    int x = (t >= off && t < BKT) ? scn[t - off] : 0;
    __syncthreads();
    if (t < BKT) { val += x; scn[t] = val; }
    __syncthreads();
  }
  if (t < BKT) {
    int ex = val - hist[t];
    excl[t] = ex;
    cur[t] = 0;
    int d = (b << 7) + t;
    if (d < n) {
      rs[d] = e0 + ex;
      dis[d] = rsqrtf((float)hist[t]);  // deg >= 1 (self-loop)
    }
  }
  if (b == 0 && t == 0) rs[n] = total;
  __syncthreads();
  for (int i = t; i < sz; i += 256) {
    int2 p = inl ? el[i] : ebuf[e0 + i];
    int dl = p.y & (BKT - 1);
    int pos = atomicAdd(&cur[dl], 1);
    ebuf2[e0 + excl[dl] + pos] = p;
  }
}

// pass D: (src,dst) -> (src, norm)
__global__ void norm_kernel(const int2* __restrict__ ebuf2, const float* __restrict__ dis,
                            int2* __restrict__ esn, int T) {
  int j = blockIdx.x * blockDim.x + threadIdx.x;
  if (j >= T) return;
  int2 p = ebuf2[j];
  float nm = dis[p.x] * dis[p.y];
  esn[j] = make_int2(p.x, __float_as_int(nm));
}

// per-wave row bounds: A[w] = first row r with rs[r] >= w*EB
__global__ void wave_bounds_kernel(const int* __restrict__ rs, int* __restrict__ A,
                                   int n, int nw, int eb) {
  int w = blockIdx.x * blockDim.x + threadIdx.x;
  if (w > nw) return;
  int target = w * eb;
  int lo = 0, hi = n;
  while (lo < hi) {
    int mid = (lo + hi) >> 1;
    if (rs[mid] < target) lo = mid + 1; else hi = mid;
  }
  A[w] = lo;
}

__global__ void softmax_w_kernel(const float* __restrict__ lw, float* __restrict__ w, int l) {
  if (threadIdx.x == 0 && blockIdx.x == 0) {
    float m = lw[0];
    for (int i = 1; i < l; ++i) m = fmaxf(m, lw[i]);
    float s = 0.f;
    for (int i = 0; i < l; ++i) s += expf(lw[i] - m);
    for (int i = 0; i < l; ++i) w[i] = expf(lw[i] - m) / s;
  }
}

// transpose conv_W to Wt[l][n][k] bf16
__global__ void transpose_w_kernel(const float* __restrict__ W, unsigned short* __restrict__ Wt,
                                   int total) {
  int t = blockIdx.x * blockDim.x + threadIdx.x;
  if (t >= total) return;
  int l = t >> 14;
  int nc = (t >> 7) & 127;
  int kk = t & 127;
  Wt[t] = f2bf(W[(size_t)l * 16384 + kk * 128 + nc]);
}

// ---------------- embed ----------------

__global__ void embed_kernel(const float* __restrict__ x, const float* __restrict__ W,
                             const float* __restrict__ b, float* __restrict__ xe,
                             unsigned short* __restrict__ xebf, int n) {
  int r = blockIdx.x * 2 + (threadIdx.x >> 7);
  int c = threadIdx.x & 127;
  if (r >= n) return;
  float acc = b[c];
#pragma unroll
  for (int k = 0; k < 16; ++k)
    acc = fmaf(x[(size_t)r * 16 + k], W[k * 128 + c], acc);
  xe[(size_t)r * 128 + c] = acc;
  xebf[(size_t)r * 128 + c] = f2bf(acc);
}

// ---------------- fused (BN+ReLU+residual of prev layer) + MFMA GEMM ----------------

template<bool HASBN>
__global__ __launch_bounds__(256) void gemm_fused_kernel(
    const unsigned short* __restrict__ Abf,   // !HASBN: bf16 input
    const unsigned* __restrict__ aggbf,       // HASBN: packed bf16x2 agg (prev layer)
    const float* __restrict__ stats8,         // HASBN: 8 slices x 256 (prev layer)
    const float* __restrict__ gamma, const float* __restrict__ beta,
    const float* __restrict__ wsm, int layer, // prev layer idx
    float* __restrict__ xe,
    const unsigned short* __restrict__ Wt,
    unsigned short* __restrict__ Hbf, int n) {
  __shared__ short8 wlds[2048];               // 32 KB
  __shared__ float sc_s[128], sh_s[128];
  int tid = threadIdx.x;
  const short* WtS = (const short*)Wt;
#pragma unroll
  for (int it = 0; it < 8; ++it) {
    int s = it * 256 + tid;
    int ln = s & 63, g = s >> 6;              // g = n0*4+ks
    int col = ((g >> 2) << 4) + (ln & 15);
    wlds[s] = *(const short8*)(WtS + (size_t)col * 128 + (g & 3) * 32 + (ln >> 4) * 8);
  }
  if (HASBN && tid < 128) {
    float s = 0.f, q = 0.f;
#pragma unroll
    for (int k = 0; k < 8; ++k) {
      s += stats8[k * 256 + tid];
      q += stats8[k * 256 + 128 + tid];
    }
    float invn = 1.f / (float)n;
    float mean = s * invn;
    float var = q * invn - mean * mean;
    float sc = gamma[tid] * rsqrtf(var + 1e-5f);
    sc_s[tid] = sc;
    sh_s[tid] = beta[tid] - mean * sc;
  }
  __syncthreads();

  int wid = tid >> 6, lane = tid & 63;
  int lrow = lane & 15, lk = lane >> 4;
  float wres = HASBN ? wsm[layer] : 0.f;

  int ntiles = (n + 63) >> 6;
  for (int tile = blockIdx.x; tile < ntiles; tile += gridDim.x) {
    int row = tile * 64 + wid * 16 + lrow;
    short8 afrag[4];
    if (row < n) {
      if (HASBN) {
        const unsigned* arow = aggbf + (size_t)row * 64;
        float* xrow = xe + (size_t)row * 128;
#pragma unroll
        for (int ks = 0; ks < 4; ++ks) {
          int c0 = ks * 32 + lk * 8;
          uint4 av = *(const uint4*)(arow + (c0 >> 1));
          float4 xa = *(const float4*)(xrow + c0);
          float4 xb = *(const float4*)(xrow + c0 + 4);
          unsigned aw[4] = {av.x, av.y, av.z, av.w};
          float xv[8] = {xa.x, xa.y, xa.z, xa.w, xb.x, xb.y, xb.z, xb.w};
          float xn[8];
          short8 af;
#pragma unroll
          for (int d = 0; d < 4; ++d) {
            int c = c0 + 2 * d;
            float v0 = fmaxf(fmaf(bf2f_lo(aw[d]), sc_s[c], sh_s[c]), 0.f);
            float v1 = fmaxf(fmaf(bf2f_hi(aw[d]), sc_s[c + 1], sh_s[c + 1]), 0.f);
            xn[2 * d]     = fmaf(wres, v0, xv[2 * d]);
            xn[2 * d + 1] = fmaf(wres, v1, xv[2 * d + 1]);
          }
          *(float4*)(xrow + c0)     = make_float4(xn[0], xn[1], xn[2], xn[3]);
          *(float4*)(xrow + c0 + 4) = make_float4(xn[4], xn[5], xn[6], xn[7]);
#pragma unroll
          for (int d2 = 0; d2 < 8; ++d2) af[d2] = (short)f2bf(xn[d2]);
          afrag[ks] = af;
        }
      } else {
        const short* AS = (const short*)Abf;
#pragma unroll
        for (int ks = 0; ks < 4; ++ks)
          afrag[ks] = *(const short8*)(AS + (size_t)row * 128 + ks * 32 + lk * 8);
      }
    } else {
#pragma unroll
      for (int ks = 0; ks < 4; ++ks) afrag[ks] = (short8)0;
    }
    f32x4 acc[8];
#pragma unroll
    for (int n0 = 0; n0 < 8; ++n0) acc[n0] = (f32x4)0.f;
#pragma unroll
    for (int ks = 0; ks < 4; ++ks)
#pragma unroll
      for (int n0 = 0; n0 < 8; ++n0)
        acc[n0] = __builtin_amdgcn_mfma_f32_16x16x32_bf16(
            afrag[ks], wlds[(n0 * 4 + ks) * 64 + lane], acc[n0], 0, 0, 0);
    int orow0 = tile * 64 + wid * 16 + lk * 4;
#pragma unroll
    for (int n0 = 0; n0 < 8; ++n0) {
      int col = n0 * 16 + lrow;
#pragma unroll
      for (int r = 0; r < 4; ++r) {
        int orow = orow0 + r;
        if (orow < n) Hbf[(size_t)orow * 128 + col] = f2bf(acc[n0][r]);
      }
    }
  }
}

// ---------------- flat segmented SpMM + fused BN stats ----------------

#define SPMM_STEP(PI, VI, EOFF)                                            \
  {                                                                        \
    float nm = __int_as_float(PI.y);                                       \
    a0 = fmaf(nm, bf2f_lo(VI), a0);                                        \
    a1 = fmaf(nm, bf2f_hi(VI), a1);                                        \
    if (e + (EOFF) + 1 == next) {                                          \
      aggbf[(size_t)row * 64 + lane] = pack_bf2(a0, a1);                   \
      s0 += a0; s1 += a1;                                                  \
      q0 = fmaf(a0, a0, q0); q1 = fmaf(a1, a1, q1);                        \
      a0 = 0.f; a1 = 0.f;                                                  \
      ++row;                                                               \
      next = (row < row_end) ? rs[row + 1] : 0x7fffffff;                   \
    }                                                                      \
  }

__global__ __launch_bounds__(256) void spmm_kernel(
    const int* __restrict__ rs, const int* __restrict__ A,
    const int2* __restrict__ esn, const unsigned* __restrict__ hb,
    unsigned* __restrict__ aggbf, float* __restrict__ stats8, int n) {
  int tid = threadIdx.x;
  int wid = tid >> 6, lane = tid & 63;
  int w = blockIdx.x * 4 + wid;
  int row = A[w], row_end = A[w + 1];
  float s0 = 0.f, s1 = 0.f, q0 = 0.f, q1 = 0.f;
  if (row < row_end) {
    int e = rs[row];
    int eend = rs[row_end];
    int next = rs[row + 1];
    float a0 = 0.f, a1 = 0.f;
    while (e + 8 <= eend) {
      int2 p0 = esn[e],     p1 = esn[e + 1], p2 = esn[e + 2], p3 = esn[e + 3];
      int2 p4 = esn[e + 4], p5 = esn[e + 5], p6 = esn[e + 6], p7 = esn[e + 7];
      unsigned v0 = hb[(size_t)p0.x * 64 + lane];
      unsigned v1 = hb[(size_t)p1.x * 64 + lane];
      unsigned v2 = hb[(size_t)p2.x * 64 + lane];
      unsigned v3 = hb[(size_t)p3.x * 64 + lane];
      unsigned v4 = hb[(size_t)p4.x * 64 + lane];
      unsigned v5 = hb[(size_t)p5.x * 64 + lane];
      unsigned v6 = hb[(size_t)p6.x * 64 + lane];
      unsigned v7 = hb[(size_t)p7.x * 64 + lane];
      SPMM_STEP(p0, v0, 0) SPMM_STEP(p1, v1, 1) SPMM_STEP(p2, v2, 2) SPMM_STEP(p3, v3, 3)
      SPMM_STEP(p4, v4, 4) SPMM_STEP(p5, v5, 5) SPMM_STEP(p6, v6, 6) SPMM_STEP(p7, v7, 7)
      e += 8;
    }
    while (e < eend) {
      int2 p = esn[e];
      unsigned v = hb[(size_t)p.x * 64 + lane];
      SPMM_STEP(p, v, 0)
      ++e;
    }
  }
  __shared__ float red[4][256];
  red[0][tid] = s0; red[1][tid] = s1; red[2][tid] = q0; red[3][tid] = q1;
  __syncthreads();
  float v = red[wid][lane] + red[wid][64 + lane] + red[wid][128 + lane] + red[wid][192 + lane];
  int c = (wid == 0) ? (2 * lane) : (wid == 1) ? (2 * lane + 1)
        : (wid == 2) ? (128 + 2 * lane) : (129 + 2 * lane);
  atomicAdd(&stats8[(blockIdx.x & 7) * 256 + c], v);
}

// ---------------- final FC (fused BN of last layer) ----------------

__global__ __launch_bounds__(256) void fc_node_kernel(
    const unsigned* __restrict__ aggbf, const float* __restrict__ stats8,
    const float* __restrict__ gamma, const float* __restrict__ beta,
    const float* __restrict__ wsm, int layer,
    const float* __restrict__ xe, const float* __restrict__ fcW,
    float* __restrict__ y, int n) {
  __shared__ float sc_s[128], sh_s[128];
  int tid = threadIdx.x;
  if (tid < 128) {
    float s = 0.f, q = 0.f;
#pragma unroll
    for (int k = 0; k < 8; ++k) {
      s += stats8[k * 256 + tid];
      q += stats8[k * 256 + 128 + tid];
    }
    float invn = 1.f / (float)n;
    float mean = s * invn;
    float var = q * invn - mean * mean;
    float sc = gamma[tid] * rsqrtf(var + 1e-5f);
    sc_s[tid] = sc;
    sh_s[tid] = beta[tid] - mean * sc;
  }
  __syncthreads();
  int wid = tid >> 6, lane = tid & 63;
  int r = blockIdx.x * 4 + wid;
  if (r >= n) return;
  float w = wsm[layer];
  unsigned av = aggbf[(size_t)r * 64 + lane];
  float2 xv = *(const float2*)(xe + (size_t)r * 128 + lane * 2);
  int c0 = lane * 2, c1 = c0 + 1;
  float x0 = fmaf(w, fmaxf(fmaf(bf2f_lo(av), sc_s[c0], sh_s[c0]), 0.f), xv.x);
  float x1 = fmaf(w, fmaxf(fmaf(bf2f_hi(av), sc_s[c1], sh_s[c1]), 0.f), xv.y);
  float a00 = x0 * fcW[c0 * 2 + 0] + x1 * fcW[c1 * 2 + 0];
  float a01 = x0 * fcW[c0 * 2 + 1] + x1 * fcW[c1 * 2 + 1];
  float a10 = x0 * fcW[(128 + c0) * 2 + 0] + x1 * fcW[(128 + c1) * 2 + 0];
  float a11 = x0 * fcW[(128 + c0) * 2 + 1] + x1 * fcW[(128 + c1) * 2 + 1];
#pragma unroll
  for (int off = 32; off; off >>= 1) {
    a00 += __shfl_down(a00, off);
    a01 += __shfl_down(a01, off);
    a10 += __shfl_down(a10, off);
    a11 += __shfl_down(a11, off);
  }
  if (lane == 0) *(float4*)(y + (size_t)r * 4) = make_float4(a00, a01, a10, a11);
}

__global__ void edge_out_kernel(const float* __restrict__ y, const int* __restrict__ eo,
                                const float* __restrict__ fcb, float* __restrict__ out, int m) {
  int j = blockIdx.x * blockDim.x + threadIdx.x;
  if (j >= m) return;
  int a = eo[j], b = eo[m + j];
  float4 ya = *(const float4*)(y + (size_t)a * 4);
  float4 yb = *(const float4*)(y + (size_t)b * 4);
  out[(size_t)j * 2 + 0] = ya.x + yb.z + fcb[0];
  out[(size_t)j * 2 + 1] = ya.y + yb.w + fcb[1];
}

// ---------------------------------------------------------------------------

extern "C" void kernel_launch(void* const* d_in, const int* in_sizes, int n_in,
                              void* d_out, int out_size, void* d_ws, size_t ws_size,
                              hipStream_t stream) {
  const float* x     = (const float*)d_in[0];
  const int*   ei    = (const int*)d_in[1];
  const int*   eo    = (const int*)d_in[2];
  const float* embW  = (const float*)d_in[3];
  const float* embB  = (const float*)d_in[4];
  const float* convW = (const float*)d_in[5];
  const float* gamma = (const float*)d_in[7];
  const float* beta  = (const float*)d_in[8];
  const float* lw    = (const float*)d_in[9];
  const float* fcW   = (const float*)d_in[10];
  const float* fcb   = (const float*)d_in[11];
  float* out = (float*)d_out;

  const int n = in_sizes[0] / 16;          // 100000
  const int e = in_sizes[1] / 2;           // 1600000
  const int m = in_sizes[2] / 2;           // 400000
  const int L = in_sizes[5] / (128 * 128); // 6

  const int T   = e + n;                   // total edges incl self loops
  const int EB  = (T + NW - 1) / NW;       // edges per wave target
  const int nbk = (n + BKT - 1) / BKT;     // 782 buckets

  const int* esrc = ei;
  const int* edst = ei + e;

  char* wsp = (char*)d_ws;
  size_t off = 0;
  auto take = [&](size_t bytes) -> void* {
    void* p = wsp + off;
    off = (off + bytes + 255) & ~(size_t)255;
    return p;
  };
  int*            bcnt     = (int*)take((size_t)(nbk + 1) * 4);
  int*            bbase    = (int*)take((size_t)(nbk + 1) * 4);
  int*            bfill    = (int*)take((size_t)(nbk + 1) * 4);
  int*            rs       = (int*)take((size_t)(n + 1) * 4);
  float*          dis      = (float*)take((size_t)n * 4);
  float*          wsm      = (float*)take(64 * 4);
  float*          stats    = (float*)take((size_t)L * 8 * 256 * 4);
  int*            A        = (int*)take((size_t)(NW + 1) * 4);
  int2*           ebuf     = (int2*)take((size_t)T * 8);   // bucketed (src,dst); reused as esn
  int2*           ebuf2    = (int2*)take((size_t)T * 8);   // sorted (src,dst)
  float*          xe       = (float*)take((size_t)n * 128 * 4);
  unsigned short* xebf     = (unsigned short*)take((size_t)n * 128 * 2);
  unsigned short* hbf      = (unsigned short*)take((size_t)n * 128 * 2);
  unsigned*       aggbf    = (unsigned*)take((size_t)n * 64 * 4);
  unsigned short* Wt       = (unsigned short*)take((size_t)L * 128 * 128 * 2);
  float*          y        = (float*)take((size_t)n * 4 * 4);
  if (off > ws_size || nbk > 1024) return;

  int2* esn = ebuf;  // alias: pass D reads ebuf2, writes into ebuf's space

  // --- preprocessing: radix sort by dst ---
  hipMemsetAsync(bcnt, 0, (size_t)(nbk + 1) * 4, stream);
  hipMemsetAsync(stats, 0, (size_t)L * 8 * 256 * 4, stream);
  hist_bucket_kernel<<<256, 256, 0, stream>>>(edst, bcnt, e, n, nbk);
  scan_buckets_kernel<<<1, 1024, 0, stream>>>(bcnt, bbase, nbk, T);
  hipMemcpyAsync(bfill, bbase, (size_t)nbk * 4, hipMemcpyDeviceToDevice, stream);
  scatter_bucket_kernel<<<256, 256, 0, stream>>>(esrc, edst, bfill, ebuf, e, n, nbk);
  sort_bucket_kernel<<<nbk, 256, 0, stream>>>(bbase, ebuf, ebuf2, rs, dis, n, T);
  norm_kernel<<<(T + 255) / 256, 256, 0, stream>>>(ebuf2, dis, esn, T);
  wave_bounds_kernel<<<(NW + 256) / 256, 256, 0, stream>>>(rs, A, n, NW, EB);
  softmax_w_kernel<<<1, 64, 0, stream>>>(lw, wsm, L);
  transpose_w_kernel<<<(L * 16384 + 255) / 256, 256, 0, stream>>>(convW, Wt, L * 16384);

  // --- embed ---
  embed_kernel<<<(n + 1) / 2, 256, 0, stream>>>(x, embW, embB, xe, xebf, n);

  // --- 6 GCN layers (conv_b dropped: cancels under BN) ---
  const int ntiles = (n + 63) >> 6;
  const int gemm_grid = (ntiles + 1) / 2;   // exactly <=2 tiles per block
  for (int i = 0; i < L; ++i) {
    if (i == 0) {
      gemm_fused_kernel<false><<<gemm_grid, 256, 0, stream>>>(
          xebf, nullptr, nullptr, nullptr, nullptr, wsm, 0, xe,
          Wt, hbf, n);
    } else {
      gemm_fused_kernel<true><<<gemm_grid, 256, 0, stream>>>(
          nullptr, aggbf, stats + (size_t)(i - 1) * 2048,
          gamma + (size_t)(i - 1) * 128, beta + (size_t)(i - 1) * 128, wsm, i - 1, xe,
          Wt + (size_t)i * 16384, hbf, n);
    }
    spmm_kernel<<<NW / 4, 256, 0, stream>>>(rs, A, esn, (const unsigned*)hbf,
                                            aggbf, stats + (size_t)i * 2048, n);
  }

  // --- final FC (fused BN of layer L-1) ---
  fc_node_kernel<<<(n + 3) / 4, 256, 0, stream>>>(
      aggbf, stats + (size_t)(L - 1) * 2048,
      gamma + (size_t)(L - 1) * 128, beta + (size_t)(L - 1) * 128, wsm, L - 1,
      xe, fcW, y, n);
  edge_out_kernel<<<(m + 255) / 256, 256, 0, stream>>>(y, eo, fcb, out, m);
}